// Round 5
// baseline (172.894 us; speedup 1.0000x reference)
//
#include <hip/hip_runtime.h>
#include <hip/hip_bf16.h>
#include <math.h>

#define NROW 65536      // I*J = 256*256
#define LOG2E_ 1.4426950408889634f
#define HSTRIDE 2097152 // 65536*32 elems per head

typedef short short8 __attribute__((ext_vector_type(8)));   // 8 x bf16 (4 VGPRs)
typedef float f32x4 __attribute__((ext_vector_type(4)));
typedef int int4v __attribute__((ext_vector_type(4)));

#if defined(__has_builtin)
#if __has_builtin(__builtin_amdgcn_exp2f)
#define EXP2F(x) __builtin_amdgcn_exp2f(x)
#else
#define EXP2F(x) exp2f(x)
#endif
#else
#define EXP2F(x) exp2f(x)
#endif

static __device__ __forceinline__ unsigned short f2bf(float f) {
    union { float f; unsigned int u; } c; c.f = f;
    c.u += 0x7fffu + ((c.u >> 16) & 1u);      // RNE (no NaN inputs here)
    return (unsigned short)(c.u >> 16);
}
static __device__ __forceinline__ float bf2f(unsigned short s) {
    union { unsigned int u; float f; } c; c.u = ((unsigned int)s) << 16;
    return c.f;
}
static __device__ __forceinline__ int pk2bf(float a, float b) {
    union { __hip_bfloat162 h; int i; } u;
    u.h = __float22bfloat162_rn(make_float2(a, b));   // x -> low 16 bits
    return u.i;
}

// ---------------------------------------------------------------------------
// Prep: W[128k][128n] fp32 -> Wt[n][k] bf16 (transposed); q_w pre-scaled by
// D^-0.5 * log2(e) so attention uses exp2 directly.
// ---------------------------------------------------------------------------
__global__ __launch_bounds__(256) void prep_w_kernel(
    const float* __restrict__ qw, const float* __restrict__ kw,
    const float* __restrict__ vw, const float* __restrict__ gw,
    const float* __restrict__ ow, unsigned short* __restrict__ wt)
{
    int id = blockIdx.x * 256 + threadIdx.x;      // 0 .. 81919
    int wsel = id >> 14;
    int e = id & 16383;
    int kk = e >> 7, n = e & 127;
    const float* src = (wsel == 0) ? qw : (wsel == 1) ? kw : (wsel == 2) ? vw
                     : (wsel == 3) ? gw : ow;
    float scale = (wsel == 0) ? (0.17677669529663687f * LOG2E_) : 1.0f;
    wt[wsel * 16384 + n * 128 + kk] = f2bf(src[kk * 128 + n] * scale);
}

// ---------------------------------------------------------------------------
// LayerNorm -> xn (bf16) + tri bias (bf16, log2e-scaled) in MFMA-tiled layout:
// triT[h][qt][kt][m][kc] : offset = h*65536 + qt*4096 + kt*256 + m*16 + kc
// ---------------------------------------------------------------------------
__global__ __launch_bounds__(256) void ln_tri_kernel(
    const float* __restrict__ x, const float* __restrict__ ln_w,
    const float* __restrict__ ln_b, const float* __restrict__ tri_w,
    unsigned short* __restrict__ xn, unsigned short* __restrict__ triT)
{
    int row  = (blockIdx.x * 256 + threadIdx.x) >> 6;
    int lane = threadIdx.x & 63;

    float2 xv = *(const float2*)(x + (size_t)row * 128 + lane * 2);

    float s = xv.x + xv.y;
    #pragma unroll
    for (int m = 32; m >= 1; m >>= 1) s += __shfl_xor(s, m, 64);
    float mu = s * (1.0f / 128.0f);

    float d0 = xv.x - mu, d1 = xv.y - mu;
    float sq = d0 * d0 + d1 * d1;
    #pragma unroll
    for (int m = 32; m >= 1; m >>= 1) sq += __shfl_xor(sq, m, 64);
    float rstd = rsqrtf(sq * (1.0f / 128.0f) + 1e-5f);

    float2 wv = *(const float2*)(ln_w + lane * 2);
    float2 bv = *(const float2*)(ln_b + lane * 2);
    float n0 = d0 * rstd * wv.x + bv.x;
    float n1 = d1 * rstd * wv.y + bv.y;

    ushort2 xo; xo.x = f2bf(n0); xo.y = f2bf(n1);
    *(ushort2*)(xn + (size_t)row * 128 + lane * 2) = xo;

    float4 t0 = *(const float4*)(tri_w + (lane * 2) * 4);
    float4 t1 = *(const float4*)(tri_w + (lane * 2 + 1) * 4);
    float ax = n0 * t0.x + n1 * t1.x;
    float ay = n0 * t0.y + n1 * t1.y;
    float az = n0 * t0.z + n1 * t1.z;
    float aw = n0 * t0.w + n1 * t1.w;
    #pragma unroll
    for (int m = 32; m >= 1; m >>= 1) {
        ax += __shfl_xor(ax, m, 64);
        ay += __shfl_xor(ay, m, 64);
        az += __shfl_xor(az, m, 64);
        aw += __shfl_xor(aw, m, 64);
    }
    if (lane < 4) {
        float v = (lane == 0) ? ax : (lane == 1) ? ay : (lane == 2) ? az : aw;
        int q = row >> 8, kc = row & 255;
        int off = lane * 65536 + (q >> 4) * 4096 + (kc >> 4) * 256
                + (q & 15) * 16 + (kc & 15);
        triT[off] = f2bf(v * LOG2E_);
    }
}

// ---------------------------------------------------------------------------
// Fused projections: xn @ {q,k,v,g}_w -> head-separated [h][65536][32] bf16.
// Swapped mfma(b,a) -> C^T layout: lane holds 4 consecutive out-cols.
// wsel==3 gets sigmoid(x + g_b).
// ---------------------------------------------------------------------------
__global__ __launch_bounds__(256) void proj4_kernel(
    const unsigned short* __restrict__ A, const unsigned short* __restrict__ wt,
    const float* __restrict__ g_b,
    unsigned short* __restrict__ qh, unsigned short* __restrict__ kh,
    unsigned short* __restrict__ vh, unsigned short* __restrict__ gh)
{
    __shared__ __align__(16) unsigned short A_lds[128 * 128];
    __shared__ __align__(16) unsigned short W_lds[128 * 128];

    const int tid = threadIdx.x;
    const int m0 = blockIdx.x * 128;
    const int w = tid >> 6, lane = tid & 63, g = lane >> 4, m = lane & 15;
    const int wr = w >> 1, wc = w & 1;

    #pragma unroll
    for (int it = 0; it < 8; ++it) {
        int idx = it * 256 + tid;
        int row = idx >> 4, c8 = idx & 15;
        short8 av = *(const short8*)(A + (size_t)(m0 + row) * 128 + c8 * 8);
        int off = (row * 256 + c8 * 16) ^ ((row & 7) << 4);
        *(short8*)((char*)A_lds + off) = av;
    }

    unsigned short* outp[4] = {qh, kh, vh, gh};
    for (int wsel = 0; wsel < 4; ++wsel) {
        __syncthreads();   // also covers A-stage on first iteration
        #pragma unroll
        for (int it = 0; it < 8; ++it) {
            int idx = it * 256 + tid;
            int row = idx >> 4, c8 = idx & 15;
            short8 wv = *(const short8*)(wt + wsel * 16384 + row * 128 + c8 * 8);
            int off = (row * 256 + c8 * 16) ^ ((row & 7) << 4);
            *(short8*)((char*)W_lds + off) = wv;
        }
        __syncthreads();

        f32x4 acc[4][4];
        #pragma unroll
        for (int mt = 0; mt < 4; ++mt)
            #pragma unroll
            for (int nt = 0; nt < 4; ++nt) acc[mt][nt] = (f32x4){0.f,0.f,0.f,0.f};

        #pragma unroll
        for (int kc = 0; kc < 4; ++kc) {
            short8 a[4], b[4];
            #pragma unroll
            for (int mt = 0; mt < 4; ++mt) {
                int row = wr * 64 + mt * 16 + m;
                a[mt] = *(const short8*)((const char*)A_lds +
                         ((row * 256 + kc * 64 + 16 * g) ^ ((row & 7) << 4)));
            }
            #pragma unroll
            for (int nt = 0; nt < 4; ++nt) {
                int row = wc * 64 + nt * 16 + m;
                b[nt] = *(const short8*)((const char*)W_lds +
                         ((row * 256 + kc * 64 + 16 * g) ^ ((row & 7) << 4)));
            }
            #pragma unroll
            for (int mt = 0; mt < 4; ++mt)
                #pragma unroll
                for (int nt = 0; nt < 4; ++nt)
                    acc[mt][nt] = __builtin_amdgcn_mfma_f32_16x16x32_bf16(
                                      b[nt], a[mt], acc[mt][nt], 0, 0, 0);
        }

        #pragma unroll
        for (int nt = 0; nt < 4; ++nt) {
            int col = wc * 64 + nt * 16 + 4 * g;
            int hsel = col >> 5, c32 = col & 31;
            unsigned short* OB = outp[wsel] + (size_t)hsel * HSTRIDE;
            float4 bv = make_float4(0.f,0.f,0.f,0.f);
            if (wsel == 3) bv = *(const float4*)(g_b + col);
            #pragma unroll
            for (int mt = 0; mt < 4; ++mt) {
                int row = m0 + wr * 64 + mt * 16 + m;
                float v0 = acc[mt][nt][0], v1 = acc[mt][nt][1];
                float v2 = acc[mt][nt][2], v3 = acc[mt][nt][3];
                if (wsel == 3) {
                    v0 = 1.0f / (1.0f + __expf(-(v0 + bv.x)));
                    v1 = 1.0f / (1.0f + __expf(-(v1 + bv.y)));
                    v2 = 1.0f / (1.0f + __expf(-(v2 + bv.z)));
                    v3 = 1.0f / (1.0f + __expf(-(v3 + bv.w)));
                }
                ushort4 o;
                o.x = f2bf(v0); o.y = f2bf(v1); o.z = f2bf(v2); o.w = f2bf(v3);
                *(ushort4*)(OB + (size_t)row * 32 + c32) = o;
            }
        }
    }
}

// ---------------------------------------------------------------------------
// Output projection: out[M,128] = og @ o_w + o_b (f32 out), og head-separated.
// ---------------------------------------------------------------------------
__global__ __launch_bounds__(256) void oproj_kernel(
    const unsigned short* __restrict__ ogh, const unsigned short* __restrict__ Wt,
    const float* __restrict__ bias, float* __restrict__ out)
{
    __shared__ __align__(16) unsigned short A_lds[128 * 128];
    __shared__ __align__(16) unsigned short W_lds[128 * 128];

    const int tid = threadIdx.x;
    const int m0 = blockIdx.x * 128;
    const int w = tid >> 6, lane = tid & 63, g = lane >> 4, m = lane & 15;
    const int wr = w >> 1, wc = w & 1;

    #pragma unroll
    for (int it = 0; it < 8; ++it) {
        int idx = it * 256 + tid;
        int row = idx >> 4, c8 = idx & 15;
        short8 av = *(const short8*)(ogh + (size_t)(c8 >> 2) * HSTRIDE
                                     + (size_t)(m0 + row) * 32 + (c8 & 3) * 8);
        short8 wv = *(const short8*)(Wt + row * 128 + c8 * 8);
        int off = (row * 256 + c8 * 16) ^ ((row & 7) << 4);
        *(short8*)((char*)A_lds + off) = av;
        *(short8*)((char*)W_lds + off) = wv;
    }
    __syncthreads();

    f32x4 acc[4][4];
    #pragma unroll
    for (int mt = 0; mt < 4; ++mt)
        #pragma unroll
        for (int nt = 0; nt < 4; ++nt) acc[mt][nt] = (f32x4){0.f,0.f,0.f,0.f};

    #pragma unroll
    for (int kc = 0; kc < 4; ++kc) {
        short8 a[4], b[4];
        #pragma unroll
        for (int mt = 0; mt < 4; ++mt) {
            int row = wr * 64 + mt * 16 + m;
            a[mt] = *(const short8*)((const char*)A_lds +
                     ((row * 256 + kc * 64 + 16 * g) ^ ((row & 7) << 4)));
        }
        #pragma unroll
        for (int nt = 0; nt < 4; ++nt) {
            int row = wc * 64 + nt * 16 + m;
            b[nt] = *(const short8*)((const char*)W_lds +
                     ((row * 256 + kc * 64 + 16 * g) ^ ((row & 7) << 4)));
        }
        #pragma unroll
        for (int mt = 0; mt < 4; ++mt)
            #pragma unroll
            for (int nt = 0; nt < 4; ++nt)
                acc[mt][nt] = __builtin_amdgcn_mfma_f32_16x16x32_bf16(
                                  b[nt], a[mt], acc[mt][nt], 0, 0, 0);
    }

    #pragma unroll
    for (int nt = 0; nt < 4; ++nt) {
        int col = wc * 64 + nt * 16 + 4 * g;
        float4 bv = *(const float4*)(bias + col);
        #pragma unroll
        for (int mt = 0; mt < 4; ++mt) {
            int row = m0 + wr * 64 + mt * 16 + m;
            float4 o;
            o.x = acc[mt][nt][0] + bv.x;
            o.y = acc[mt][nt][1] + bv.y;
            o.z = acc[mt][nt][2] + bv.z;
            o.w = acc[mt][nt][3] + bv.w;
            *(float4*)(out + (size_t)row * 128 + col) = o;
        }
    }
}

// ---------------------------------------------------------------------------
// MFMA attention, block per (i,h). Fused score->exchange->PV per 32-key
// chunk: only 4 pk scalars live (no spillable array, no union). bit_cast
// keeps the exchanged fragment in SSA registers.
// ---------------------------------------------------------------------------
__global__ __launch_bounds__(256, 4) void attn_kernel(
    const unsigned short* __restrict__ qh, const unsigned short* __restrict__ kh,
    const unsigned short* __restrict__ vh, const unsigned short* __restrict__ gh,
    const float* __restrict__ mask, const unsigned short* __restrict__ triT,
    unsigned short* __restrict__ ogh)
{
    __shared__ __align__(16) unsigned short K_lds[256 * 40];   // 80B rows
    __shared__ __align__(16) unsigned short Vc[32 * 264];      // col-major, pad
    __shared__ float mb[256];

    const int i = blockIdx.x, h = blockIdx.y;
    const int tid = threadIdx.x;
    const int w = tid >> 6, lane = tid & 63, g = lane >> 4, m = lane & 15;
    const size_t hb = (size_t)h * HSTRIDE + (size_t)i * 8192;   // [h][i*256][32]

    #pragma unroll
    for (int it = 0; it < 4; ++it) {
        int idx = it * 256 + tid;
        int j = idx >> 2, d0 = (idx & 3) * 8;
        short8 kv = *(const short8*)(kh + hb + (size_t)j * 32 + d0);
        short8 vv = *(const short8*)(vh + hb + (size_t)j * 32 + d0);
        *(short8*)((char*)K_lds + j * 80 + d0 * 2) = kv;
        unsigned short* vp = (unsigned short*)&vv;
        #pragma unroll
        for (int e = 0; e < 8; ++e) Vc[(d0 + e) * 264 + j] = vp[e];
    }
    mb[tid] = (mask[i * 256 + tid] - 1.0f) * (1.0e9f * LOG2E_);
    __syncthreads();

    // bpermute lane indices: classA srcs [0,2,1,3], classB = srcA^1
    const int srcA = ((g & 1) << 1) | (g >> 1);
    const int idxA = (srcA * 16 + m) * 4;
    const int idxB = idxA ^ 64;
    const bool low = (lane < 32);
    const bool odd = (g & 1);
    const char* VcB0 = (const char*)Vc + m * 528;
    const char* VcB1 = (const char*)Vc + (16 + m) * 528;
    const f32x4 zero = {0.f, 0.f, 0.f, 0.f};
    // tiled tri base for this lane: + qt*4096 + kt*256 at use
    const unsigned short* triL = triT + h * 65536 + m * 16 + 4 * g;

    #pragma unroll 1
    for (int t = 0; t < 4; ++t) {
        const int qrow = w * 64 + t * 16 + m;
        const short8 qf = *(const short8*)(qh + hb + (size_t)qrow * 32 + 8 * g);
        const unsigned short* triQ = triL + (w * 4 + t) * 4096;

        float ls = 0.f;
        f32x4 o0 = zero, o1 = zero;

        #pragma unroll
        for (int c = 0; c < 8; ++c) {
            int d00, d01, d10, d11;
            {
                const int kt = 2 * c;
                short8 af = *(const short8*)((const char*)K_lds + (kt * 16 + m) * 80 + 16 * g);
                f32x4 acc = __builtin_amdgcn_mfma_f32_16x16x32_bf16(af, qf, zero, 0, 0, 0);
                f32x4 mbv = *(const f32x4*)(mb + kt * 16 + 4 * g);
                int2 td = *(const int2*)(triQ + kt * 256);
                float t0 = __uint_as_float((unsigned)td.x << 16);
                float t1 = __uint_as_float((unsigned)td.x & 0xffff0000u);
                float t2 = __uint_as_float((unsigned)td.y << 16);
                float t3 = __uint_as_float((unsigned)td.y & 0xffff0000u);
                float p0 = EXP2F(acc[0] + mbv[0] + t0);
                float p1 = EXP2F(acc[1] + mbv[1] + t1);
                float p2 = EXP2F(acc[2] + mbv[2] + t2);
                float p3 = EXP2F(acc[3] + mbv[3] + t3);
                ls += (p0 + p1) + (p2 + p3);
                d00 = pk2bf(p0, p1); d01 = pk2bf(p2, p3);
            }
            {
                const int kt = 2 * c + 1;
                short8 af = *(const short8*)((const char*)K_lds + (kt * 16 + m) * 80 + 16 * g);
                f32x4 acc = __builtin_amdgcn_mfma_f32_16x16x32_bf16(af, qf, zero, 0, 0, 0);
                f32x4 mbv = *(const f32x4*)(mb + kt * 16 + 4 * g);
                int2 td = *(const int2*)(triQ + kt * 256);
                float t0 = __uint_as_float((unsigned)td.x << 16);
                float t1 = __uint_as_float((unsigned)td.x & 0xffff0000u);
                float t2 = __uint_as_float((unsigned)td.y << 16);
                float t3 = __uint_as_float((unsigned)td.y & 0xffff0000u);
                float p0 = EXP2F(acc[0] + mbv[0] + t0);
                float p1 = EXP2F(acc[1] + mbv[1] + t1);
                float p2 = EXP2F(acc[2] + mbv[2] + t2);
                float p3 = EXP2F(acc[3] + mbv[3] + t3);
                ls += (p0 + p1) + (p2 + p3);
                d10 = pk2bf(p0, p1); d11 = pk2bf(p2, p3);
            }
            // parity relabel: odd g-groups store kt^1 in the kt slot-pair
            int pk0 = odd ? d10 : d00;
            int pk1 = odd ? d11 : d01;
            int pk2 = odd ? d00 : d10;
            int pk3 = odd ? d01 : d11;

            int dA0 = __builtin_amdgcn_ds_bpermute(idxA, pk0);
            int dA1 = __builtin_amdgcn_ds_bpermute(idxA, pk1);
            int dB0 = __builtin_amdgcn_ds_bpermute(idxB, pk2);
            int dB1 = __builtin_amdgcn_ds_bpermute(idxB, pk3);
            int4v bi;
            bi.x = low ? dA0 : dB0;
            bi.y = low ? dA1 : dB1;
            bi.z = low ? dB0 : dA0;
            bi.w = low ? dB1 : dA1;
            short8 bs = __builtin_bit_cast(short8, bi);

            short8 av0 = *(const short8*)(VcB0 + c * 64 + 16 * g);
            short8 av1 = *(const short8*)(VcB1 + c * 64 + 16 * g);
            o0 = __builtin_amdgcn_mfma_f32_16x16x32_bf16(av0, bs, o0, 0, 0, 0);
            o1 = __builtin_amdgcn_mfma_f32_16x16x32_bf16(av1, bs, o1, 0, 0, 0);
        }
        ls += __shfl_xor(ls, 16, 64);
        ls += __shfl_xor(ls, 32, 64);

        float inv = 1.0f / ls;
        size_t ro = hb + (size_t)qrow * 32;
        ushort4 g0 = *(const ushort4*)(gh + ro + 4 * g);
        ushort4 g1 = *(const ushort4*)(gh + ro + 16 + 4 * g);
        ushort4 s0, s1;
        s0.x = f2bf(o0[0] * inv * bf2f(g0.x));
        s0.y = f2bf(o0[1] * inv * bf2f(g0.y));
        s0.z = f2bf(o0[2] * inv * bf2f(g0.z));
        s0.w = f2bf(o0[3] * inv * bf2f(g0.w));
        s1.x = f2bf(o1[0] * inv * bf2f(g1.x));
        s1.y = f2bf(o1[1] * inv * bf2f(g1.y));
        s1.z = f2bf(o1[2] * inv * bf2f(g1.z));
        s1.w = f2bf(o1[3] * inv * bf2f(g1.w));
        *(ushort4*)(ogh + ro + 4 * g) = s0;
        *(ushort4*)(ogh + ro + 16 + 4 * g) = s1;
    }
}

// ---------------------------------------------------------------------------
extern "C" void kernel_launch(void* const* d_in, const int* in_sizes, int n_in,
                              void* d_out, int out_size, void* d_ws, size_t ws_size,
                              hipStream_t stream) {
    (void)in_sizes; (void)n_in; (void)out_size; (void)ws_size;
    const float* x    = (const float*)d_in[0];
    const float* mask = (const float*)d_in[1];
    const float* ln_w = (const float*)d_in[2];
    const float* ln_b = (const float*)d_in[3];
    const float* tri_w= (const float*)d_in[4];
    const float* q_w  = (const float*)d_in[5];
    const float* k_w  = (const float*)d_in[6];
    const float* v_w  = (const float*)d_in[7];
    const float* g_w  = (const float*)d_in[8];
    const float* g_b  = (const float*)d_in[9];
    const float* o_w  = (const float*)d_in[10];
    const float* o_b  = (const float*)d_in[11];

    char* ws = (char*)d_ws;
    unsigned short* xn  = (unsigned short*)(ws);                 // 16 MB
    unsigned short* qhp = (unsigned short*)(ws + 16777216);      // [4][65536][32]
    unsigned short* khp = (unsigned short*)(ws + 33554432);
    unsigned short* vhp = (unsigned short*)(ws + 50331648);
    unsigned short* ghp = (unsigned short*)(ws + 67108864);
    unsigned short* ogh = (unsigned short*)(ws + 83886080);
    unsigned short* tri = (unsigned short*)(ws + 100663296);     // 512 KB tiled
    unsigned short* wt  = (unsigned short*)(ws + 101711872);     // 160 KB

    prep_w_kernel<<<320, 256, 0, stream>>>(q_w, k_w, v_w, g_w, o_w, wt);
    ln_tri_kernel<<<16384, 256, 0, stream>>>(x, ln_w, ln_b, tri_w, xn, tri);

    proj4_kernel<<<512, 256, 0, stream>>>(xn, wt, g_b, qhp, khp, vhp, ghp);

    dim3 ga(256, 4);
    attn_kernel<<<ga, 256, 0, stream>>>(qhp, khp, vhp, ghp, mask, tri, ogh);

    oproj_kernel<<<512, 256, 0, stream>>>(ogh, wt + 65536, o_b, (float*)d_out);
}

// Round 6
// 122.384 us; speedup vs baseline: 1.4127x; 1.4127x over previous
//
#include <hip/hip_runtime.h>
#include <hip/hip_bf16.h>
#include <math.h>

#define NROW 65536      // I*J = 256*256
#define LOG2E_ 1.4426950408889634f
#define HSTRIDE 2097152 // 65536*32 elems per head

typedef short short8 __attribute__((ext_vector_type(8)));   // 8 x bf16 (4 VGPRs)
typedef float f32x4 __attribute__((ext_vector_type(4)));
typedef int int4v __attribute__((ext_vector_type(4)));

#if defined(__has_builtin)
#if __has_builtin(__builtin_amdgcn_exp2f)
#define EXP2F(x) __builtin_amdgcn_exp2f(x)
#else
#define EXP2F(x) exp2f(x)
#endif
#else
#define EXP2F(x) exp2f(x)
#endif

static __device__ __forceinline__ unsigned short f2bf(float f) {
    union { float f; unsigned int u; } c; c.f = f;
    c.u += 0x7fffu + ((c.u >> 16) & 1u);      // RNE (no NaN inputs here)
    return (unsigned short)(c.u >> 16);
}
static __device__ __forceinline__ float bf2f(unsigned short s) {
    union { unsigned int u; float f; } c; c.u = ((unsigned int)s) << 16;
    return c.f;
}
static __device__ __forceinline__ int pk2bf(float a, float b) {
    union { __hip_bfloat162 h; int i; } u;
    u.h = __float22bfloat162_rn(make_float2(a, b));   // x -> low 16 bits
    return u.i;
}

// ---------------------------------------------------------------------------
// Prep: W[128k][128n] fp32 -> Wt[n][k] bf16 (transposed); q_w pre-scaled by
// D^-0.5 * log2(e) so attention uses exp2 directly.
// ---------------------------------------------------------------------------
__global__ __launch_bounds__(256) void prep_w_kernel(
    const float* __restrict__ qw, const float* __restrict__ kw,
    const float* __restrict__ vw, const float* __restrict__ gw,
    const float* __restrict__ ow, unsigned short* __restrict__ wt)
{
    int id = blockIdx.x * 256 + threadIdx.x;      // 0 .. 81919
    int wsel = id >> 14;
    int e = id & 16383;
    int kk = e >> 7, n = e & 127;
    const float* src = (wsel == 0) ? qw : (wsel == 1) ? kw : (wsel == 2) ? vw
                     : (wsel == 3) ? gw : ow;
    float scale = (wsel == 0) ? (0.17677669529663687f * LOG2E_) : 1.0f;
    wt[wsel * 16384 + n * 128 + kk] = f2bf(src[kk * 128 + n] * scale);
}

// ---------------------------------------------------------------------------
// LayerNorm -> xn (bf16) + tri bias (bf16, log2e-scaled) in MFMA-tiled layout:
// triT[h][qt][kt][m][kc] : offset = h*65536 + qt*4096 + kt*256 + m*16 + kc
// ---------------------------------------------------------------------------
__global__ __launch_bounds__(256) void ln_tri_kernel(
    const float* __restrict__ x, const float* __restrict__ ln_w,
    const float* __restrict__ ln_b, const float* __restrict__ tri_w,
    unsigned short* __restrict__ xn, unsigned short* __restrict__ triT)
{
    int row  = (blockIdx.x * 256 + threadIdx.x) >> 6;
    int lane = threadIdx.x & 63;

    float2 xv = *(const float2*)(x + (size_t)row * 128 + lane * 2);

    float s = xv.x + xv.y;
    #pragma unroll
    for (int m = 32; m >= 1; m >>= 1) s += __shfl_xor(s, m, 64);
    float mu = s * (1.0f / 128.0f);

    float d0 = xv.x - mu, d1 = xv.y - mu;
    float sq = d0 * d0 + d1 * d1;
    #pragma unroll
    for (int m = 32; m >= 1; m >>= 1) sq += __shfl_xor(sq, m, 64);
    float rstd = rsqrtf(sq * (1.0f / 128.0f) + 1e-5f);

    float2 wv = *(const float2*)(ln_w + lane * 2);
    float2 bv = *(const float2*)(ln_b + lane * 2);
    float n0 = d0 * rstd * wv.x + bv.x;
    float n1 = d1 * rstd * wv.y + bv.y;

    ushort2 xo; xo.x = f2bf(n0); xo.y = f2bf(n1);
    *(ushort2*)(xn + (size_t)row * 128 + lane * 2) = xo;

    float4 t0 = *(const float4*)(tri_w + (lane * 2) * 4);
    float4 t1 = *(const float4*)(tri_w + (lane * 2 + 1) * 4);
    float ax = n0 * t0.x + n1 * t1.x;
    float ay = n0 * t0.y + n1 * t1.y;
    float az = n0 * t0.z + n1 * t1.z;
    float aw = n0 * t0.w + n1 * t1.w;
    #pragma unroll
    for (int m = 32; m >= 1; m >>= 1) {
        ax += __shfl_xor(ax, m, 64);
        ay += __shfl_xor(ay, m, 64);
        az += __shfl_xor(az, m, 64);
        aw += __shfl_xor(aw, m, 64);
    }
    if (lane < 4) {
        float v = (lane == 0) ? ax : (lane == 1) ? ay : (lane == 2) ? az : aw;
        int q = row >> 8, kc = row & 255;
        int off = lane * 65536 + (q >> 4) * 4096 + (kc >> 4) * 256
                + (q & 15) * 16 + (kc & 15);
        triT[off] = f2bf(v * LOG2E_);
    }
}

// ---------------------------------------------------------------------------
// Fused projections: xn @ {q,k,v,g}_w -> head-separated [h][65536][32] bf16.
// Swapped mfma(b,a) -> C^T layout: lane holds 4 consecutive out-cols.
// wsel==3 gets sigmoid(x + g_b).
// ---------------------------------------------------------------------------
__global__ __launch_bounds__(256) void proj4_kernel(
    const unsigned short* __restrict__ A, const unsigned short* __restrict__ wt,
    const float* __restrict__ g_b,
    unsigned short* __restrict__ qh, unsigned short* __restrict__ kh,
    unsigned short* __restrict__ vh, unsigned short* __restrict__ gh)
{
    __shared__ __align__(16) unsigned short A_lds[128 * 128];
    __shared__ __align__(16) unsigned short W_lds[128 * 128];

    const int tid = threadIdx.x;
    const int m0 = blockIdx.x * 128;
    const int w = tid >> 6, lane = tid & 63, g = lane >> 4, m = lane & 15;
    const int wr = w >> 1, wc = w & 1;

    #pragma unroll
    for (int it = 0; it < 8; ++it) {
        int idx = it * 256 + tid;
        int row = idx >> 4, c8 = idx & 15;
        short8 av = *(const short8*)(A + (size_t)(m0 + row) * 128 + c8 * 8);
        int off = (row * 256 + c8 * 16) ^ ((row & 7) << 4);
        *(short8*)((char*)A_lds + off) = av;
    }

    unsigned short* outp[4] = {qh, kh, vh, gh};
    for (int wsel = 0; wsel < 4; ++wsel) {
        __syncthreads();   // also covers A-stage on first iteration
        #pragma unroll
        for (int it = 0; it < 8; ++it) {
            int idx = it * 256 + tid;
            int row = idx >> 4, c8 = idx & 15;
            short8 wv = *(const short8*)(wt + wsel * 16384 + row * 128 + c8 * 8);
            int off = (row * 256 + c8 * 16) ^ ((row & 7) << 4);
            *(short8*)((char*)W_lds + off) = wv;
        }
        __syncthreads();

        f32x4 acc[4][4];
        #pragma unroll
        for (int mt = 0; mt < 4; ++mt)
            #pragma unroll
            for (int nt = 0; nt < 4; ++nt) acc[mt][nt] = (f32x4){0.f,0.f,0.f,0.f};

        #pragma unroll
        for (int kc = 0; kc < 4; ++kc) {
            short8 a[4], b[4];
            #pragma unroll
            for (int mt = 0; mt < 4; ++mt) {
                int row = wr * 64 + mt * 16 + m;
                a[mt] = *(const short8*)((const char*)A_lds +
                         ((row * 256 + kc * 64 + 16 * g) ^ ((row & 7) << 4)));
            }
            #pragma unroll
            for (int nt = 0; nt < 4; ++nt) {
                int row = wc * 64 + nt * 16 + m;
                b[nt] = *(const short8*)((const char*)W_lds +
                         ((row * 256 + kc * 64 + 16 * g) ^ ((row & 7) << 4)));
            }
            #pragma unroll
            for (int mt = 0; mt < 4; ++mt)
                #pragma unroll
                for (int nt = 0; nt < 4; ++nt)
                    acc[mt][nt] = __builtin_amdgcn_mfma_f32_16x16x32_bf16(
                                      b[nt], a[mt], acc[mt][nt], 0, 0, 0);
        }

        #pragma unroll
        for (int nt = 0; nt < 4; ++nt) {
            int col = wc * 64 + nt * 16 + 4 * g;
            int hsel = col >> 5, c32 = col & 31;
            unsigned short* OB = outp[wsel] + (size_t)hsel * HSTRIDE;
            float4 bv = make_float4(0.f,0.f,0.f,0.f);
            if (wsel == 3) bv = *(const float4*)(g_b + col);
            #pragma unroll
            for (int mt = 0; mt < 4; ++mt) {
                int row = m0 + wr * 64 + mt * 16 + m;
                float v0 = acc[mt][nt][0], v1 = acc[mt][nt][1];
                float v2 = acc[mt][nt][2], v3 = acc[mt][nt][3];
                if (wsel == 3) {
                    v0 = 1.0f / (1.0f + __expf(-(v0 + bv.x)));
                    v1 = 1.0f / (1.0f + __expf(-(v1 + bv.y)));
                    v2 = 1.0f / (1.0f + __expf(-(v2 + bv.z)));
                    v3 = 1.0f / (1.0f + __expf(-(v3 + bv.w)));
                }
                ushort4 o;
                o.x = f2bf(v0); o.y = f2bf(v1); o.z = f2bf(v2); o.w = f2bf(v3);
                *(ushort4*)(OB + (size_t)row * 32 + c32) = o;
            }
        }
    }
}

// ---------------------------------------------------------------------------
// Output projection: out[M,128] = og @ o_w + o_b (f32 out), og head-separated.
// ---------------------------------------------------------------------------
__global__ __launch_bounds__(256) void oproj_kernel(
    const unsigned short* __restrict__ ogh, const unsigned short* __restrict__ Wt,
    const float* __restrict__ bias, float* __restrict__ out)
{
    __shared__ __align__(16) unsigned short A_lds[128 * 128];
    __shared__ __align__(16) unsigned short W_lds[128 * 128];

    const int tid = threadIdx.x;
    const int m0 = blockIdx.x * 128;
    const int w = tid >> 6, lane = tid & 63, g = lane >> 4, m = lane & 15;
    const int wr = w >> 1, wc = w & 1;

    #pragma unroll
    for (int it = 0; it < 8; ++it) {
        int idx = it * 256 + tid;
        int row = idx >> 4, c8 = idx & 15;
        short8 av = *(const short8*)(ogh + (size_t)(c8 >> 2) * HSTRIDE
                                     + (size_t)(m0 + row) * 32 + (c8 & 3) * 8);
        short8 wv = *(const short8*)(Wt + row * 128 + c8 * 8);
        int off = (row * 256 + c8 * 16) ^ ((row & 7) << 4);
        *(short8*)((char*)A_lds + off) = av;
        *(short8*)((char*)W_lds + off) = wv;
    }
    __syncthreads();

    f32x4 acc[4][4];
    #pragma unroll
    for (int mt = 0; mt < 4; ++mt)
        #pragma unroll
        for (int nt = 0; nt < 4; ++nt) acc[mt][nt] = (f32x4){0.f,0.f,0.f,0.f};

    #pragma unroll
    for (int kc = 0; kc < 4; ++kc) {
        short8 a[4], b[4];
        #pragma unroll
        for (int mt = 0; mt < 4; ++mt) {
            int row = wr * 64 + mt * 16 + m;
            a[mt] = *(const short8*)((const char*)A_lds +
                     ((row * 256 + kc * 64 + 16 * g) ^ ((row & 7) << 4)));
        }
        #pragma unroll
        for (int nt = 0; nt < 4; ++nt) {
            int row = wc * 64 + nt * 16 + m;
            b[nt] = *(const short8*)((const char*)W_lds +
                     ((row * 256 + kc * 64 + 16 * g) ^ ((row & 7) << 4)));
        }
        #pragma unroll
        for (int mt = 0; mt < 4; ++mt)
            #pragma unroll
            for (int nt = 0; nt < 4; ++nt)
                acc[mt][nt] = __builtin_amdgcn_mfma_f32_16x16x32_bf16(
                                  b[nt], a[mt], acc[mt][nt], 0, 0, 0);
    }

    #pragma unroll
    for (int nt = 0; nt < 4; ++nt) {
        int col = wc * 64 + nt * 16 + 4 * g;
        float4 bv = *(const float4*)(bias + col);
        #pragma unroll
        for (int mt = 0; mt < 4; ++mt) {
            int row = m0 + wr * 64 + mt * 16 + m;
            float4 o;
            o.x = acc[mt][nt][0] + bv.x;
            o.y = acc[mt][nt][1] + bv.y;
            o.z = acc[mt][nt][2] + bv.z;
            o.w = acc[mt][nt][3] + bv.w;
            *(float4*)(out + (size_t)row * 128 + col) = o;
        }
    }
}

// ---------------------------------------------------------------------------
// MFMA attention, block per (i,h). Fused score->exchange->PV per 32-key
// chunk. launch_bounds(256,2): VGPR cap 128 (no spill; rounds 3-5's
// (256,3/4) caps of 84/64 forced 90-115 MB of scratch traffic).
// ---------------------------------------------------------------------------
__global__ __launch_bounds__(256, 2) void attn_kernel(
    const unsigned short* __restrict__ qh, const unsigned short* __restrict__ kh,
    const unsigned short* __restrict__ vh, const unsigned short* __restrict__ gh,
    const float* __restrict__ mask, const unsigned short* __restrict__ triT,
    unsigned short* __restrict__ ogh)
{
    __shared__ __align__(16) unsigned short K_lds[256 * 40];   // 80B rows
    __shared__ __align__(16) unsigned short Vc[32 * 264];      // col-major, pad
    __shared__ float mb[256];

    const int i = blockIdx.x, h = blockIdx.y;
    const int tid = threadIdx.x;
    const int w = tid >> 6, lane = tid & 63, g = lane >> 4, m = lane & 15;
    const size_t hb = (size_t)h * HSTRIDE + (size_t)i * 8192;   // [h][i*256][32]

    #pragma unroll
    for (int it = 0; it < 4; ++it) {
        int idx = it * 256 + tid;
        int j = idx >> 2, d0 = (idx & 3) * 8;
        short8 kv = *(const short8*)(kh + hb + (size_t)j * 32 + d0);
        short8 vv = *(const short8*)(vh + hb + (size_t)j * 32 + d0);
        *(short8*)((char*)K_lds + j * 80 + d0 * 2) = kv;
        #pragma unroll
        for (int e = 0; e < 8; ++e)
            Vc[(d0 + e) * 264 + j] = (unsigned short)vv[e];
    }
    mb[tid] = (mask[i * 256 + tid] - 1.0f) * (1.0e9f * LOG2E_);
    __syncthreads();

    // bpermute lane indices: classA srcs [0,2,1,3], classB = srcA^1
    const int srcA = ((g & 1) << 1) | (g >> 1);
    const int idxA = (srcA * 16 + m) * 4;
    const int idxB = idxA ^ 64;
    const bool low = (lane < 32);
    const bool odd = (g & 1);
    const char* VcB0 = (const char*)Vc + m * 528;
    const char* VcB1 = (const char*)Vc + (16 + m) * 528;
    const f32x4 zero = {0.f, 0.f, 0.f, 0.f};
    // tiled tri base for this lane: + qt*4096 + kt*256 at use
    const unsigned short* triL = triT + h * 65536 + m * 16 + 4 * g;

    #pragma unroll 1
    for (int t = 0; t < 4; ++t) {
        const int qrow = w * 64 + t * 16 + m;
        const short8 qf = *(const short8*)(qh + hb + (size_t)qrow * 32 + 8 * g);
        const unsigned short* triQ = triL + (w * 4 + t) * 4096;

        float ls = 0.f;
        f32x4 o0 = zero, o1 = zero;

        #pragma unroll
        for (int c = 0; c < 8; ++c) {
            int d00, d01, d10, d11;
            {
                const int kt = 2 * c;
                short8 af = *(const short8*)((const char*)K_lds + (kt * 16 + m) * 80 + 16 * g);
                f32x4 acc = __builtin_amdgcn_mfma_f32_16x16x32_bf16(af, qf, zero, 0, 0, 0);
                f32x4 mbv = *(const f32x4*)(mb + kt * 16 + 4 * g);
                int2 td = *(const int2*)(triQ + kt * 256);
                float t0 = __uint_as_float((unsigned)td.x << 16);
                float t1 = __uint_as_float((unsigned)td.x & 0xffff0000u);
                float t2 = __uint_as_float((unsigned)td.y << 16);
                float t3 = __uint_as_float((unsigned)td.y & 0xffff0000u);
                float p0 = EXP2F(acc[0] + mbv[0] + t0);
                float p1 = EXP2F(acc[1] + mbv[1] + t1);
                float p2 = EXP2F(acc[2] + mbv[2] + t2);
                float p3 = EXP2F(acc[3] + mbv[3] + t3);
                ls += (p0 + p1) + (p2 + p3);
                d00 = pk2bf(p0, p1); d01 = pk2bf(p2, p3);
            }
            {
                const int kt = 2 * c + 1;
                short8 af = *(const short8*)((const char*)K_lds + (kt * 16 + m) * 80 + 16 * g);
                f32x4 acc = __builtin_amdgcn_mfma_f32_16x16x32_bf16(af, qf, zero, 0, 0, 0);
                f32x4 mbv = *(const f32x4*)(mb + kt * 16 + 4 * g);
                int2 td = *(const int2*)(triQ + kt * 256);
                float t0 = __uint_as_float((unsigned)td.x << 16);
                float t1 = __uint_as_float((unsigned)td.x & 0xffff0000u);
                float t2 = __uint_as_float((unsigned)td.y << 16);
                float t3 = __uint_as_float((unsigned)td.y & 0xffff0000u);
                float p0 = EXP2F(acc[0] + mbv[0] + t0);
                float p1 = EXP2F(acc[1] + mbv[1] + t1);
                float p2 = EXP2F(acc[2] + mbv[2] + t2);
                float p3 = EXP2F(acc[3] + mbv[3] + t3);
                ls += (p0 + p1) + (p2 + p3);
                d10 = pk2bf(p0, p1); d11 = pk2bf(p2, p3);
            }
            // parity relabel: odd g-groups store kt^1 in the kt slot-pair
            int pk0 = odd ? d10 : d00;
            int pk1 = odd ? d11 : d01;
            int pk2 = odd ? d00 : d10;
            int pk3 = odd ? d01 : d11;

            int dA0 = __builtin_amdgcn_ds_bpermute(idxA, pk0);
            int dA1 = __builtin_amdgcn_ds_bpermute(idxA, pk1);
            int dB0 = __builtin_amdgcn_ds_bpermute(idxB, pk2);
            int dB1 = __builtin_amdgcn_ds_bpermute(idxB, pk3);
            int4v bi;
            bi.x = low ? dA0 : dB0;
            bi.y = low ? dA1 : dB1;
            bi.z = low ? dB0 : dA0;
            bi.w = low ? dB1 : dA1;
            short8 bs = __builtin_bit_cast(short8, bi);

            short8 av0 = *(const short8*)(VcB0 + c * 64 + 16 * g);
            short8 av1 = *(const short8*)(VcB1 + c * 64 + 16 * g);
            o0 = __builtin_amdgcn_mfma_f32_16x16x32_bf16(av0, bs, o0, 0, 0, 0);
            o1 = __builtin_amdgcn_mfma_f32_16x16x32_bf16(av1, bs, o1, 0, 0, 0);
        }
        ls += __shfl_xor(ls, 16, 64);
        ls += __shfl_xor(ls, 32, 64);

        float inv = 1.0f / ls;
        size_t ro = hb + (size_t)qrow * 32;
        ushort4 g0 = *(const ushort4*)(gh + ro + 4 * g);
        ushort4 g1 = *(const ushort4*)(gh + ro + 16 + 4 * g);
        ushort4 s0, s1;
        s0.x = f2bf(o0[0] * inv * bf2f(g0.x));
        s0.y = f2bf(o0[1] * inv * bf2f(g0.y));
        s0.z = f2bf(o0[2] * inv * bf2f(g0.z));
        s0.w = f2bf(o0[3] * inv * bf2f(g0.w));
        s1.x = f2bf(o1[0] * inv * bf2f(g1.x));
        s1.y = f2bf(o1[1] * inv * bf2f(g1.y));
        s1.z = f2bf(o1[2] * inv * bf2f(g1.z));
        s1.w = f2bf(o1[3] * inv * bf2f(g1.w));
        *(ushort4*)(ogh + ro + 4 * g) = s0;
        *(ushort4*)(ogh + ro + 16 + 4 * g) = s1;
    }
}

// ---------------------------------------------------------------------------
extern "C" void kernel_launch(void* const* d_in, const int* in_sizes, int n_in,
                              void* d_out, int out_size, void* d_ws, size_t ws_size,
                              hipStream_t stream) {
    (void)in_sizes; (void)n_in; (void)out_size; (void)ws_size;
    const float* x    = (const float*)d_in[0];
    const float* mask = (const float*)d_in[1];
    const float* ln_w = (const float*)d_in[2];
    const float* ln_b = (const float*)d_in[3];
    const float* tri_w= (const float*)d_in[4];
    const float* q_w  = (const float*)d_in[5];
    const float* k_w  = (const float*)d_in[6];
    const float* v_w  = (const float*)d_in[7];
    const float* g_w  = (const float*)d_in[8];
    const float* g_b  = (const float*)d_in[9];
    const float* o_w  = (const float*)d_in[10];
    const float* o_b  = (const float*)d_in[11];

    char* ws = (char*)d_ws;
    unsigned short* xn  = (unsigned short*)(ws);                 // 16 MB
    unsigned short* qhp = (unsigned short*)(ws + 16777216);      // [4][65536][32]
    unsigned short* khp = (unsigned short*)(ws + 33554432);
    unsigned short* vhp = (unsigned short*)(ws + 50331648);
    unsigned short* ghp = (unsigned short*)(ws + 67108864);
    unsigned short* ogh = (unsigned short*)(ws + 83886080);
    unsigned short* tri = (unsigned short*)(ws + 100663296);     // 512 KB tiled
    unsigned short* wt  = (unsigned short*)(ws + 101711872);     // 160 KB

    prep_w_kernel<<<320, 256, 0, stream>>>(q_w, k_w, v_w, g_w, o_w, wt);
    ln_tri_kernel<<<16384, 256, 0, stream>>>(x, ln_w, ln_b, tri_w, xn, tri);

    proj4_kernel<<<512, 256, 0, stream>>>(xn, wt, g_b, qhp, khp, vhp, ghp);

    dim3 ga(256, 4);
    attn_kernel<<<ga, 256, 0, stream>>>(qhp, khp, vhp, ghp, mask, tri, ogh);

    oproj_kernel<<<512, 256, 0, stream>>>(ogh, wt + 65536, o_b, (float*)d_out);
}

// Round 7
// 110.458 us; speedup vs baseline: 1.5652x; 1.1080x over previous
//
#include <hip/hip_runtime.h>
#include <hip/hip_bf16.h>
#include <math.h>

#define LOG2E_ 1.4426950408889634f

typedef short short8 __attribute__((ext_vector_type(8)));   // 8 x bf16 (4 VGPRs)
typedef float f32x4 __attribute__((ext_vector_type(4)));
typedef int int4v __attribute__((ext_vector_type(4)));

#if defined(__has_builtin)
#if __has_builtin(__builtin_amdgcn_exp2f)
#define EXP2F(x) __builtin_amdgcn_exp2f(x)
#else
#define EXP2F(x) exp2f(x)
#endif
#else
#define EXP2F(x) exp2f(x)
#endif

static __device__ __forceinline__ unsigned short f2bf(float f) {
    union { float f; unsigned int u; } c; c.f = f;
    c.u += 0x7fffu + ((c.u >> 16) & 1u);      // RNE (no NaN inputs here)
    return (unsigned short)(c.u >> 16);
}
static __device__ __forceinline__ int pk2bf(float a, float b) {
    union { __hip_bfloat162 h; int i; } u;
    u.h = __float22bfloat162_rn(make_float2(a, b));   // x -> low 16 bits
    return u.i;
}

// ---------------------------------------------------------------------------
// Prep: W[128k][128n] fp32 -> Wt[n][k] bf16 (transposed); q_w pre-scaled by
// D^-0.5 * log2(e).
// ---------------------------------------------------------------------------
__global__ __launch_bounds__(256) void prep_w_kernel(
    const float* __restrict__ qw, const float* __restrict__ kw,
    const float* __restrict__ vw, const float* __restrict__ gw,
    const float* __restrict__ ow, unsigned short* __restrict__ wt)
{
    int id = blockIdx.x * 256 + threadIdx.x;      // 0 .. 81919
    int wsel = id >> 14;
    int e = id & 16383;
    int kk = e >> 7, n = e & 127;
    const float* src = (wsel == 0) ? qw : (wsel == 1) ? kw : (wsel == 2) ? vw
                     : (wsel == 3) ? gw : ow;
    float scale = (wsel == 0) ? (0.17677669529663687f * LOG2E_) : 1.0f;
    wt[wsel * 16384 + n * 128 + kk] = f2bf(src[kk * 128 + n] * scale);
}

// ---------------------------------------------------------------------------
// LayerNorm -> xn (bf16) + tri bias (bf16, log2e-scaled) in MFMA-tiled layout:
// triT[h][qt][kt][m][kc] : offset = h*65536 + qt*4096 + kt*256 + m*16 + kc
// (tri is broadcast over i: indexed by local q,k only)
// ---------------------------------------------------------------------------
__global__ __launch_bounds__(256) void ln_tri_kernel(
    const float* __restrict__ x, const float* __restrict__ ln_w,
    const float* __restrict__ ln_b, const float* __restrict__ tri_w,
    unsigned short* __restrict__ xn, unsigned short* __restrict__ triT)
{
    int row  = (blockIdx.x * 256 + threadIdx.x) >> 6;
    int lane = threadIdx.x & 63;

    float2 xv = *(const float2*)(x + (size_t)row * 128 + lane * 2);

    float s = xv.x + xv.y;
    #pragma unroll
    for (int m = 32; m >= 1; m >>= 1) s += __shfl_xor(s, m, 64);
    float mu = s * (1.0f / 128.0f);

    float d0 = xv.x - mu, d1 = xv.y - mu;
    float sq = d0 * d0 + d1 * d1;
    #pragma unroll
    for (int m = 32; m >= 1; m >>= 1) sq += __shfl_xor(sq, m, 64);
    float rstd = rsqrtf(sq * (1.0f / 128.0f) + 1e-5f);

    float2 wv = *(const float2*)(ln_w + lane * 2);
    float2 bv = *(const float2*)(ln_b + lane * 2);
    float n0 = d0 * rstd * wv.x + bv.x;
    float n1 = d1 * rstd * wv.y + bv.y;

    ushort2 xo; xo.x = f2bf(n0); xo.y = f2bf(n1);
    *(ushort2*)(xn + (size_t)row * 128 + lane * 2) = xo;

    float4 t0 = *(const float4*)(tri_w + (lane * 2) * 4);
    float4 t1 = *(const float4*)(tri_w + (lane * 2 + 1) * 4);
    float ax = n0 * t0.x + n1 * t1.x;
    float ay = n0 * t0.y + n1 * t1.y;
    float az = n0 * t0.z + n1 * t1.z;
    float aw = n0 * t0.w + n1 * t1.w;
    #pragma unroll
    for (int m = 32; m >= 1; m >>= 1) {
        ax += __shfl_xor(ax, m, 64);
        ay += __shfl_xor(ay, m, 64);
        az += __shfl_xor(az, m, 64);
        aw += __shfl_xor(aw, m, 64);
    }
    if (lane < 4) {
        float v = (lane == 0) ? ax : (lane == 1) ? ay : (lane == 2) ? az : aw;
        int q = row >> 8, kc = row & 255;
        int off = lane * 65536 + (q >> 4) * 4096 + (kc >> 4) * 256
                + (q & 15) * 16 + (kc & 15);
        triT[off] = f2bf(v * LOG2E_);
    }
}

// ---------------------------------------------------------------------------
// Mega kernel: per i-block (256 blocks x 512 threads = 8 waves).
// Stages xn tile once; per head: W-slice staging -> Q/K/V/G projections into
// LDS (gate stays in registers), attention (fused score/exchange/PV), OG
// overwrites Q buffer, partial output projection accumulates in registers.
// ---------------------------------------------------------------------------
__global__ __launch_bounds__(512) void mega_kernel(
    const unsigned short* __restrict__ xn, const unsigned short* __restrict__ wt,
    const float* __restrict__ g_b, const float* __restrict__ mask,
    const unsigned short* __restrict__ triT, const float* __restrict__ o_b,
    float* __restrict__ out)
{
    __shared__ __align__(16) unsigned short X[32768];      // 64KB swizzled [256][128]
    __shared__ __align__(16) unsigned short WBUF[8192];    // 16KB
    __shared__ __align__(16) unsigned short Qg[256 * 40];  // Q, then OG (20KB)
    __shared__ __align__(16) unsigned short Kl[256 * 40];  // 20KB
    __shared__ __align__(16) unsigned short Vc[32 * 264];  // col-major V (16.5KB)
    __shared__ float mb[256];

    const int i = blockIdx.x;
    const int tid = threadIdx.x;
    const int w = tid >> 6, lane = tid & 63, g = lane >> 4, m = lane & 15;
    const f32x4 zero = {0.f, 0.f, 0.f, 0.f};

    // ---- stage X tile (swizzled) + mask bias
    #pragma unroll
    for (int it = 0; it < 8; ++it) {
        int idx = it * 512 + tid;
        int row = idx >> 4, c8 = idx & 15;
        short8 v = *(const short8*)(xn + (size_t)(i * 256 + row) * 128 + c8 * 8);
        *(short8*)((char*)X + ((row * 256 + c8 * 16) ^ ((row & 7) << 4))) = v;
    }
    if (tid < 256) mb[tid] = (mask[i * 256 + tid] - 1.0f) * (1.0e9f * LOG2E_);

    // bpermute exchange constants (per-wave)
    const int srcA = ((g & 1) << 1) | (g >> 1);
    const int idxA = (srcA * 16 + m) * 4;
    const int idxB = idxA ^ 64;
    const bool low = (lane < 32);
    const bool odd = (g & 1);
    const char* VcB0 = (const char*)Vc + m * 528;
    const char* VcB1 = (const char*)Vc + (16 + m) * 528;

    f32x4 oacc[2][8];
    #pragma unroll
    for (int mt = 0; mt < 2; ++mt)
        #pragma unroll
        for (int nt = 0; nt < 8; ++nt) oacc[mt][nt] = zero;

    #pragma unroll 1
    for (int h = 0; h < 4; ++h) {
        // ================= phase 1: stage Wq + Wk slices =================
        __syncthreads();
        #pragma unroll
        for (int s = 0; s < 2; ++s) {
            int elem = (s * 512 + tid) * 8;
            int sl = elem >> 12, e = elem & 4095;
            int row = e >> 7, c8 = (e >> 3) & 15;
            short8 v = *(const short8*)(wt + sl * 16384 + (h * 32 + row) * 128 + c8 * 8);
            *(short8*)((char*)WBUF + sl * 8192 +
                       ((row * 256 + c8 * 16) ^ ((row & 7) << 4))) = v;
        }
        __syncthreads();

        // ================= phase 2: project Q and K ======================
        {
            f32x4 aq[2][2], ak[2][2];
            #pragma unroll
            for (int mt = 0; mt < 2; ++mt)
                #pragma unroll
                for (int nt = 0; nt < 2; ++nt) { aq[mt][nt] = zero; ak[mt][nt] = zero; }
            #pragma unroll
            for (int kc = 0; kc < 4; ++kc) {
                short8 a[2], bq[2], bk[2];
                #pragma unroll
                for (int mt = 0; mt < 2; ++mt) {
                    int row = w * 32 + mt * 16 + m;
                    a[mt] = *(const short8*)((const char*)X +
                             ((row * 256 + kc * 64 + 16 * g) ^ ((row & 7) << 4)));
                }
                #pragma unroll
                for (int nt = 0; nt < 2; ++nt) {
                    int row = nt * 16 + m;
                    int off = (row * 256 + kc * 64 + 16 * g) ^ ((row & 7) << 4);
                    bq[nt] = *(const short8*)((const char*)WBUF + off);
                    bk[nt] = *(const short8*)((const char*)WBUF + 8192 + off);
                }
                #pragma unroll
                for (int mt = 0; mt < 2; ++mt)
                    #pragma unroll
                    for (int nt = 0; nt < 2; ++nt) {
                        aq[mt][nt] = __builtin_amdgcn_mfma_f32_16x16x32_bf16(bq[nt], a[mt], aq[mt][nt], 0, 0, 0);
                        ak[mt][nt] = __builtin_amdgcn_mfma_f32_16x16x32_bf16(bk[nt], a[mt], ak[mt][nt], 0, 0, 0);
                    }
            }
            #pragma unroll
            for (int mt = 0; mt < 2; ++mt)
                #pragma unroll
                for (int nt = 0; nt < 2; ++nt) {
                    int row = w * 32 + mt * 16 + m;
                    int col = nt * 16 + 4 * g;
                    ushort4 q4, k4;
                    q4.x = f2bf(aq[mt][nt][0]); q4.y = f2bf(aq[mt][nt][1]);
                    q4.z = f2bf(aq[mt][nt][2]); q4.w = f2bf(aq[mt][nt][3]);
                    k4.x = f2bf(ak[mt][nt][0]); k4.y = f2bf(ak[mt][nt][1]);
                    k4.z = f2bf(ak[mt][nt][2]); k4.w = f2bf(ak[mt][nt][3]);
                    *(ushort4*)(Qg + row * 40 + col) = q4;
                    *(ushort4*)(Kl + row * 40 + col) = k4;
                }
        }
        __syncthreads();

        // ================= phase 3: stage Wv + Wg ========================
        #pragma unroll
        for (int s = 0; s < 2; ++s) {
            int elem = (s * 512 + tid) * 8;
            int sl = elem >> 12, e = elem & 4095;
            int row = e >> 7, c8 = (e >> 3) & 15;
            short8 v = *(const short8*)(wt + (2 + sl) * 16384 + (h * 32 + row) * 128 + c8 * 8);
            *(short8*)((char*)WBUF + sl * 8192 +
                       ((row * 256 + c8 * 16) ^ ((row & 7) << 4))) = v;
        }
        __syncthreads();

        // ================= phase 4: project V and G (gate -> regs) =======
        f32x4 gacc[2][2];
        {
            f32x4 av[2][2];
            #pragma unroll
            for (int mt = 0; mt < 2; ++mt)
                #pragma unroll
                for (int nt = 0; nt < 2; ++nt) { av[mt][nt] = zero; gacc[mt][nt] = zero; }
            #pragma unroll
            for (int kc = 0; kc < 4; ++kc) {
                short8 a[2], bv[2], bg[2];
                #pragma unroll
                for (int mt = 0; mt < 2; ++mt) {
                    int row = w * 32 + mt * 16 + m;
                    a[mt] = *(const short8*)((const char*)X +
                             ((row * 256 + kc * 64 + 16 * g) ^ ((row & 7) << 4)));
                }
                #pragma unroll
                for (int nt = 0; nt < 2; ++nt) {
                    int row = nt * 16 + m;
                    int off = (row * 256 + kc * 64 + 16 * g) ^ ((row & 7) << 4);
                    bv[nt] = *(const short8*)((const char*)WBUF + off);
                    bg[nt] = *(const short8*)((const char*)WBUF + 8192 + off);
                }
                #pragma unroll
                for (int mt = 0; mt < 2; ++mt)
                    #pragma unroll
                    for (int nt = 0; nt < 2; ++nt) {
                        av[mt][nt]   = __builtin_amdgcn_mfma_f32_16x16x32_bf16(bv[nt], a[mt], av[mt][nt], 0, 0, 0);
                        gacc[mt][nt] = __builtin_amdgcn_mfma_f32_16x16x32_bf16(bg[nt], a[mt], gacc[mt][nt], 0, 0, 0);
                    }
            }
            #pragma unroll
            for (int mt = 0; mt < 2; ++mt)
                #pragma unroll
                for (int nt = 0; nt < 2; ++nt) {
                    int row = w * 32 + mt * 16 + m;
                    int col = nt * 16 + 4 * g;
                    #pragma unroll
                    for (int r = 0; r < 4; ++r) {
                        Vc[(col + r) * 264 + row] = f2bf(av[mt][nt][r]);
                        gacc[mt][nt][r] = 1.0f / (1.0f + __expf(-(gacc[mt][nt][r] + g_b[h * 32 + col + r])));
                    }
                }
        }
        __syncthreads();

        // ================= phase 5: attention (2 q-tiles per wave) =======
        #pragma unroll
        for (int t = 0; t < 2; ++t) {
            const int qrow = w * 32 + t * 16 + m;
            const short8 qf = *(const short8*)((const char*)Qg + qrow * 80 + 16 * g);
            const unsigned short* triQ = triT + h * 65536 + (w * 2 + t) * 4096 + m * 16 + 4 * g;

            float ls = 0.f;
            f32x4 o0 = zero, o1 = zero;

            #pragma unroll
            for (int c = 0; c < 8; ++c) {
                int d00, d01, d10, d11;
                {
                    const int kt = 2 * c;
                    short8 af = *(const short8*)((const char*)Kl + (kt * 16 + m) * 80 + 16 * g);
                    f32x4 acc = __builtin_amdgcn_mfma_f32_16x16x32_bf16(af, qf, zero, 0, 0, 0);
                    f32x4 mbv = *(const f32x4*)(mb + kt * 16 + 4 * g);
                    int2 td = *(const int2*)(triQ + kt * 256);
                    float t0 = __uint_as_float((unsigned)td.x << 16);
                    float t1 = __uint_as_float((unsigned)td.x & 0xffff0000u);
                    float t2 = __uint_as_float((unsigned)td.y << 16);
                    float t3 = __uint_as_float((unsigned)td.y & 0xffff0000u);
                    float p0 = EXP2F(acc[0] + mbv[0] + t0);
                    float p1 = EXP2F(acc[1] + mbv[1] + t1);
                    float p2 = EXP2F(acc[2] + mbv[2] + t2);
                    float p3 = EXP2F(acc[3] + mbv[3] + t3);
                    ls += (p0 + p1) + (p2 + p3);
                    d00 = pk2bf(p0, p1); d01 = pk2bf(p2, p3);
                }
                {
                    const int kt = 2 * c + 1;
                    short8 af = *(const short8*)((const char*)Kl + (kt * 16 + m) * 80 + 16 * g);
                    f32x4 acc = __builtin_amdgcn_mfma_f32_16x16x32_bf16(af, qf, zero, 0, 0, 0);
                    f32x4 mbv = *(const f32x4*)(mb + kt * 16 + 4 * g);
                    int2 td = *(const int2*)(triQ + kt * 256);
                    float t0 = __uint_as_float((unsigned)td.x << 16);
                    float t1 = __uint_as_float((unsigned)td.x & 0xffff0000u);
                    float t2 = __uint_as_float((unsigned)td.y << 16);
                    float t3 = __uint_as_float((unsigned)td.y & 0xffff0000u);
                    float p0 = EXP2F(acc[0] + mbv[0] + t0);
                    float p1 = EXP2F(acc[1] + mbv[1] + t1);
                    float p2 = EXP2F(acc[2] + mbv[2] + t2);
                    float p3 = EXP2F(acc[3] + mbv[3] + t3);
                    ls += (p0 + p1) + (p2 + p3);
                    d10 = pk2bf(p0, p1); d11 = pk2bf(p2, p3);
                }
                int pk0 = odd ? d10 : d00;
                int pk1 = odd ? d11 : d01;
                int pk2 = odd ? d00 : d10;
                int pk3 = odd ? d01 : d11;

                int dA0 = __builtin_amdgcn_ds_bpermute(idxA, pk0);
                int dA1 = __builtin_amdgcn_ds_bpermute(idxA, pk1);
                int dB0 = __builtin_amdgcn_ds_bpermute(idxB, pk2);
                int dB1 = __builtin_amdgcn_ds_bpermute(idxB, pk3);
                int4v bi;
                bi.x = low ? dA0 : dB0;
                bi.y = low ? dA1 : dB1;
                bi.z = low ? dB0 : dA0;
                bi.w = low ? dB1 : dA1;
                short8 bs = __builtin_bit_cast(short8, bi);

                short8 av0 = *(const short8*)(VcB0 + c * 64 + 16 * g);
                short8 av1 = *(const short8*)(VcB1 + c * 64 + 16 * g);
                o0 = __builtin_amdgcn_mfma_f32_16x16x32_bf16(av0, bs, o0, 0, 0, 0);
                o1 = __builtin_amdgcn_mfma_f32_16x16x32_bf16(av1, bs, o1, 0, 0, 0);
            }
            ls += __shfl_xor(ls, 16, 64);
            ls += __shfl_xor(ls, 32, 64);
            float inv = 1.0f / ls;

            ushort4 s0, s1;
            s0.x = f2bf(o0[0] * inv * gacc[t][0][0]);
            s0.y = f2bf(o0[1] * inv * gacc[t][0][1]);
            s0.z = f2bf(o0[2] * inv * gacc[t][0][2]);
            s0.w = f2bf(o0[3] * inv * gacc[t][0][3]);
            s1.x = f2bf(o1[0] * inv * gacc[t][1][0]);
            s1.y = f2bf(o1[1] * inv * gacc[t][1][1]);
            s1.z = f2bf(o1[2] * inv * gacc[t][1][2]);
            s1.w = f2bf(o1[3] * inv * gacc[t][1][3]);
            *(ushort4*)(Qg + qrow * 40 + 4 * g) = s0;          // OG aliases Q
            *(ushort4*)(Qg + qrow * 40 + 16 + 4 * g) = s1;
        }

        // stage Wo slice [128n][32k] pitch 40 (WBUF free during attention)
        {
            int n = tid >> 2, k8 = (tid & 3) * 8;
            short8 v = *(const short8*)(wt + 4 * 16384 + n * 128 + h * 32 + k8);
            *(short8*)((char*)WBUF + n * 80 + k8 * 2) = v;
        }
        __syncthreads();

        // ================= phase 6: partial output projection ============
        {
            short8 a[2], b[8];
            #pragma unroll
            for (int mt = 0; mt < 2; ++mt) {
                int row = w * 32 + mt * 16 + m;
                a[mt] = *(const short8*)((const char*)Qg + row * 80 + 16 * g);
            }
            #pragma unroll
            for (int nt = 0; nt < 8; ++nt) {
                int row = nt * 16 + m;
                b[nt] = *(const short8*)((const char*)WBUF + row * 80 + 16 * g);
            }
            #pragma unroll
            for (int mt = 0; mt < 2; ++mt)
                #pragma unroll
                for (int nt = 0; nt < 8; ++nt)
                    oacc[mt][nt] = __builtin_amdgcn_mfma_f32_16x16x32_bf16(b[nt], a[mt], oacc[mt][nt], 0, 0, 0);
        }
    }

    // ================= final epilogue: + o_b, fp32 store =================
    #pragma unroll
    for (int mt = 0; mt < 2; ++mt) {
        int row = i * 256 + w * 32 + mt * 16 + m;
        #pragma unroll
        for (int nt = 0; nt < 8; ++nt) {
            int col = nt * 16 + 4 * g;
            float4 bv = *(const float4*)(o_b + col);
            float4 o;
            o.x = oacc[mt][nt][0] + bv.x;
            o.y = oacc[mt][nt][1] + bv.y;
            o.z = oacc[mt][nt][2] + bv.z;
            o.w = oacc[mt][nt][3] + bv.w;
            *(float4*)(out + (size_t)row * 128 + col) = o;
        }
    }
}

// ---------------------------------------------------------------------------
extern "C" void kernel_launch(void* const* d_in, const int* in_sizes, int n_in,
                              void* d_out, int out_size, void* d_ws, size_t ws_size,
                              hipStream_t stream) {
    (void)in_sizes; (void)n_in; (void)out_size; (void)ws_size;
    const float* x    = (const float*)d_in[0];
    const float* mask = (const float*)d_in[1];
    const float* ln_w = (const float*)d_in[2];
    const float* ln_b = (const float*)d_in[3];
    const float* tri_w= (const float*)d_in[4];
    const float* q_w  = (const float*)d_in[5];
    const float* k_w  = (const float*)d_in[6];
    const float* v_w  = (const float*)d_in[7];
    const float* g_w  = (const float*)d_in[8];
    const float* g_b  = (const float*)d_in[9];
    const float* o_w  = (const float*)d_in[10];
    const float* o_b  = (const float*)d_in[11];

    char* ws = (char*)d_ws;
    unsigned short* xn  = (unsigned short*)(ws);                 // 16 MB
    unsigned short* tri = (unsigned short*)(ws + 16777216);      // 512 KB tiled
    unsigned short* wt  = (unsigned short*)(ws + 17301504);      // 160 KB

    prep_w_kernel<<<320, 256, 0, stream>>>(q_w, k_w, v_w, g_w, o_w, wt);
    ln_tri_kernel<<<16384, 256, 0, stream>>>(x, ln_w, ln_b, tri_w, xn, tri);

    mega_kernel<<<256, 512, 0, stream>>>(xn, wt, g_b, mask, tri, o_b,
                                         (float*)d_out);
}

// Round 8
// 75.476 us; speedup vs baseline: 2.2907x; 1.4635x over previous
//
#include <hip/hip_runtime.h>
#include <hip/hip_bf16.h>
#include <math.h>

#define LOG2E_ 1.4426950408889634f

typedef short short8 __attribute__((ext_vector_type(8)));   // 8 x bf16 (4 VGPRs)
typedef float f32x4 __attribute__((ext_vector_type(4)));
typedef int int4v __attribute__((ext_vector_type(4)));

#if defined(__has_builtin)
#if __has_builtin(__builtin_amdgcn_exp2f)
#define EXP2F(x) __builtin_amdgcn_exp2f(x)
#else
#define EXP2F(x) exp2f(x)
#endif
#else
#define EXP2F(x) exp2f(x)
#endif

static __device__ __forceinline__ unsigned short f2bf(float f) {
    union { float f; unsigned int u; } c; c.f = f;
    c.u += 0x7fffu + ((c.u >> 16) & 1u);      // RNE (no NaN inputs here)
    return (unsigned short)(c.u >> 16);
}
static __device__ __forceinline__ int pk2bf(float a, float b) {
    union { __hip_bfloat162 h; int i; } u;
    u.h = __float22bfloat162_rn(make_float2(a, b));   // x -> low 16 bits
    return u.i;
}

// ---------------------------------------------------------------------------
// Fused LN + tri (tiled layout) + weight prep.
// blocks 0..8191: LN (8 rows/block, float4, 2 rows/wave)
// blocks 8192..8511: W[128k][128n] fp32 -> Wt[n][k] bf16 (q_w pre-scaled)
// triT[h][qt][kt][m][kc] : off = h*65536 + qt*4096 + kt*256 + m*16 + kc
// ---------------------------------------------------------------------------
__global__ __launch_bounds__(256) void ln_prep_kernel(
    const float* __restrict__ x, const float* __restrict__ ln_w,
    const float* __restrict__ ln_b, const float* __restrict__ tri_w,
    const float* __restrict__ qw, const float* __restrict__ kw,
    const float* __restrict__ vw, const float* __restrict__ gw,
    const float* __restrict__ ow,
    unsigned short* __restrict__ xn, unsigned short* __restrict__ triT,
    unsigned short* __restrict__ wt)
{
    const int bid = blockIdx.x, tid = threadIdx.x;
    if (bid >= 8192) {
        int id = (bid - 8192) * 256 + tid;      // 0 .. 81919
        int wsel = id >> 14;
        int e = id & 16383;
        int kk = e >> 7, n = e & 127;
        const float* src = (wsel == 0) ? qw : (wsel == 1) ? kw : (wsel == 2) ? vw
                         : (wsel == 3) ? gw : ow;
        float scale = (wsel == 0) ? (0.17677669529663687f * LOG2E_) : 1.0f;
        wt[wsel * 16384 + n * 128 + kk] = f2bf(src[kk * 128 + n] * scale);
        return;
    }

    const int row = bid * 8 + (tid >> 5);
    const int l = tid & 31;

    float4 xv = *(const float4*)(x + (size_t)row * 128 + l * 4);
    float s = (xv.x + xv.y) + (xv.z + xv.w);
    #pragma unroll
    for (int mk = 16; mk >= 1; mk >>= 1) s += __shfl_xor(s, mk, 64);
    float mu = s * (1.0f / 128.0f);

    float d0 = xv.x - mu, d1 = xv.y - mu, d2 = xv.z - mu, d3 = xv.w - mu;
    float sq = (d0 * d0 + d1 * d1) + (d2 * d2 + d3 * d3);
    #pragma unroll
    for (int mk = 16; mk >= 1; mk >>= 1) sq += __shfl_xor(sq, mk, 64);
    float rstd = rsqrtf(sq * (1.0f / 128.0f) + 1e-5f);

    float4 wv = *(const float4*)(ln_w + l * 4);
    float4 bv = *(const float4*)(ln_b + l * 4);
    float n0 = d0 * rstd * wv.x + bv.x;
    float n1 = d1 * rstd * wv.y + bv.y;
    float n2 = d2 * rstd * wv.z + bv.z;
    float n3 = d3 * rstd * wv.w + bv.w;

    ushort4 xo;
    xo.x = f2bf(n0); xo.y = f2bf(n1); xo.z = f2bf(n2); xo.w = f2bf(n3);
    *(ushort4*)(xn + (size_t)row * 128 + l * 4) = xo;

    float4 t0 = *(const float4*)(tri_w + (l * 4 + 0) * 4);
    float4 t1 = *(const float4*)(tri_w + (l * 4 + 1) * 4);
    float4 t2 = *(const float4*)(tri_w + (l * 4 + 2) * 4);
    float4 t3 = *(const float4*)(tri_w + (l * 4 + 3) * 4);
    float ax = (n0 * t0.x + n1 * t1.x) + (n2 * t2.x + n3 * t3.x);
    float ay = (n0 * t0.y + n1 * t1.y) + (n2 * t2.y + n3 * t3.y);
    float az = (n0 * t0.z + n1 * t1.z) + (n2 * t2.z + n3 * t3.z);
    float aw = (n0 * t0.w + n1 * t1.w) + (n2 * t2.w + n3 * t3.w);
    #pragma unroll
    for (int mk = 16; mk >= 1; mk >>= 1) {
        ax += __shfl_xor(ax, mk, 64);
        ay += __shfl_xor(ay, mk, 64);
        az += __shfl_xor(az, mk, 64);
        aw += __shfl_xor(aw, mk, 64);
    }
    if (l < 4) {
        float v = (l == 0) ? ax : (l == 1) ? ay : (l == 2) ? az : aw;
        int q = row >> 8, kc = row & 255;
        int off = l * 65536 + (q >> 4) * 4096 + (kc >> 4) * 256
                + (q & 15) * 16 + (kc & 15);
        triT[off] = f2bf(v * LOG2E_);
    }
}

// ---------------------------------------------------------------------------
// Mega kernel: 256 blocks x 1024 threads (16 waves, 4/SIMD).
// X in registers (per-wave 16 rows). Per head: double-buffered 5-slice W
// stage (async prefetch of h+1 under attention), proj Q/K then V/G (gate in
// regs), attention (fused score/exchange/PV), OG over Q rows (wave-local),
// partial oproj accumulated in regs. 2 barriers per head.
// ---------------------------------------------------------------------------
__global__ __launch_bounds__(1024) void mega_kernel(
    const unsigned short* __restrict__ xn, const unsigned short* __restrict__ wt,
    const float* __restrict__ g_b, const float* __restrict__ mask,
    const unsigned short* __restrict__ triT, const float* __restrict__ o_b,
    float* __restrict__ out)
{
    __shared__ __align__(16) char WBUF[2 * 43008];         // qkvg 4x8KB + wo 10KB
    __shared__ __align__(16) unsigned short Qg[256 * 40];  // Q then OG (20KB)
    __shared__ __align__(16) unsigned short Kl[256 * 40];  // 20KB
    __shared__ __align__(16) unsigned short Vc[32 * 264];  // col-major V (16.5KB)
    __shared__ float mb[256];

    const int i = blockIdx.x;
    const int tid = threadIdx.x;
    const int w = tid >> 6, lane = tid & 63, g = lane >> 4, m = lane & 15;
    const f32x4 zero = {0.f, 0.f, 0.f, 0.f};

    // ---- X fragments in registers: this wave's 16 rows
    short8 xa[4];
    #pragma unroll
    for (int kc = 0; kc < 4; ++kc)
        xa[kc] = *(const short8*)(xn + (size_t)(i * 256 + w * 16 + m) * 128
                                  + kc * 32 + 8 * g);
    if (tid < 256) mb[tid] = (mask[i * 256 + tid] - 1.0f) * (1.0e9f * LOG2E_);

    // ---- prologue: stage head-0 weights into WBUF[0]
    #pragma unroll
    for (int it = 0; it < 3; ++it) {
        int gi = it * 1024 + tid;
        if (gi < 2048) {
            int sl = gi >> 9, e = gi & 511, row = e >> 4, c8 = e & 15;
            short8 v = *(const short8*)(wt + sl * 16384 + row * 128 + c8 * 8);
            *(short8*)(WBUF + sl * 8192 +
                       ((row * 256 + c8 * 16) ^ ((row & 7) << 4))) = v;
        } else if (gi < 2560) {
            int go = gi - 2048, n = go >> 2, k8 = go & 3;
            short8 v = *(const short8*)(wt + 65536 + n * 128 + k8 * 8);
            *(short8*)(WBUF + 32768 + n * 80 + k8 * 16) = v;
        }
    }
    __syncthreads();

    // bpermute exchange constants
    const int srcA = ((g & 1) << 1) | (g >> 1);
    const int idxA = (srcA * 16 + m) * 4;
    const int idxB = idxA ^ 64;
    const bool low = (lane < 32);
    const bool odd = (g & 1);
    const char* VcB0 = (const char*)Vc + m * 528;
    const char* VcB1 = (const char*)Vc + (16 + m) * 528;

    f32x4 oacc[8];
    #pragma unroll
    for (int nt = 0; nt < 8; ++nt) oacc[nt] = zero;

    const int qrow = w * 16 + m;

    #pragma unroll 1
    for (int h = 0; h < 4; ++h) {
        const char* wb = WBUF + (h & 1) * 43008;

        // ===== proj pass A: Q and K =====
        {
            f32x4 aq[2] = {zero, zero}, ak[2] = {zero, zero};
            #pragma unroll
            for (int kc = 0; kc < 4; ++kc) {
                short8 b0[2], b1[2];
                #pragma unroll
                for (int nt = 0; nt < 2; ++nt) {
                    int row = nt * 16 + m;
                    int off = (row * 256 + kc * 64 + 16 * g) ^ ((row & 7) << 4);
                    b0[nt] = *(const short8*)(wb + off);
                    b1[nt] = *(const short8*)(wb + 8192 + off);
                }
                #pragma unroll
                for (int nt = 0; nt < 2; ++nt) {
                    aq[nt] = __builtin_amdgcn_mfma_f32_16x16x32_bf16(b0[nt], xa[kc], aq[nt], 0, 0, 0);
                    ak[nt] = __builtin_amdgcn_mfma_f32_16x16x32_bf16(b1[nt], xa[kc], ak[nt], 0, 0, 0);
                }
            }
            #pragma unroll
            for (int nt = 0; nt < 2; ++nt) {
                int col = nt * 16 + 4 * g;
                ushort4 q4, k4;
                q4.x = f2bf(aq[nt][0]); q4.y = f2bf(aq[nt][1]);
                q4.z = f2bf(aq[nt][2]); q4.w = f2bf(aq[nt][3]);
                k4.x = f2bf(ak[nt][0]); k4.y = f2bf(ak[nt][1]);
                k4.z = f2bf(ak[nt][2]); k4.w = f2bf(ak[nt][3]);
                *(ushort4*)(Qg + qrow * 40 + col) = q4;
                *(ushort4*)(Kl + qrow * 40 + col) = k4;
            }
        }

        // ===== proj pass B: V and G (gate -> regs) =====
        f32x4 gacc[2];
        {
            f32x4 av4[2] = {zero, zero}, ag[2] = {zero, zero};
            #pragma unroll
            for (int kc = 0; kc < 4; ++kc) {
                short8 b0[2], b1[2];
                #pragma unroll
                for (int nt = 0; nt < 2; ++nt) {
                    int row = nt * 16 + m;
                    int off = (row * 256 + kc * 64 + 16 * g) ^ ((row & 7) << 4);
                    b0[nt] = *(const short8*)(wb + 16384 + off);
                    b1[nt] = *(const short8*)(wb + 24576 + off);
                }
                #pragma unroll
                for (int nt = 0; nt < 2; ++nt) {
                    av4[nt] = __builtin_amdgcn_mfma_f32_16x16x32_bf16(b0[nt], xa[kc], av4[nt], 0, 0, 0);
                    ag[nt]  = __builtin_amdgcn_mfma_f32_16x16x32_bf16(b1[nt], xa[kc], ag[nt], 0, 0, 0);
                }
            }
            #pragma unroll
            for (int nt = 0; nt < 2; ++nt) {
                int col = nt * 16 + 4 * g;
                #pragma unroll
                for (int r = 0; r < 4; ++r) {
                    Vc[(col + r) * 264 + qrow] = f2bf(av4[nt][r]);
                    gacc[nt][r] = 1.0f / (1.0f + __expf(-(ag[nt][r] + g_b[h * 32 + col + r])));
                }
            }
        }

        // ===== async prefetch of head h+1 weights (issue loads only) =====
        short8 sv0, sv1, sv2;
        if (h < 3) {
            int hh = h + 1;
            { int sl = tid >> 9, e = tid & 511, row = e >> 4, c8 = e & 15;
              sv0 = *(const short8*)(wt + sl * 16384 + (hh * 32 + row) * 128 + c8 * 8); }
            { int gi = 1024 + tid; int sl = gi >> 9, e = gi & 511, row = e >> 4, c8 = e & 15;
              sv1 = *(const short8*)(wt + sl * 16384 + (hh * 32 + row) * 128 + c8 * 8); }
            if (tid < 512) { int n = tid >> 2, k8 = tid & 3;
              sv2 = *(const short8*)(wt + 65536 + n * 128 + hh * 32 + k8 * 8); }
        }
        __syncthreads();   // proj writes -> attn reads

        // ===== attention: this wave's q-tile =====
        const short8 qf = *(const short8*)((const char*)Qg + qrow * 80 + 16 * g);
        const unsigned short* triQ = triT + h * 65536 + w * 4096 + m * 16 + 4 * g;

        float ls = 0.f;
        f32x4 o0 = zero, o1 = zero;

        #pragma unroll
        for (int c = 0; c < 8; ++c) {
            int d00, d01, d10, d11;
            {
                const int kt = 2 * c;
                short8 af = *(const short8*)((const char*)Kl + (kt * 16 + m) * 80 + 16 * g);
                f32x4 acc = __builtin_amdgcn_mfma_f32_16x16x32_bf16(af, qf, zero, 0, 0, 0);
                f32x4 mbv = *(const f32x4*)(mb + kt * 16 + 4 * g);
                int2 td = *(const int2*)(triQ + kt * 256);
                float t0 = __uint_as_float((unsigned)td.x << 16);
                float t1 = __uint_as_float((unsigned)td.x & 0xffff0000u);
                float t2 = __uint_as_float((unsigned)td.y << 16);
                float t3 = __uint_as_float((unsigned)td.y & 0xffff0000u);
                float p0 = EXP2F(acc[0] + mbv[0] + t0);
                float p1 = EXP2F(acc[1] + mbv[1] + t1);
                float p2 = EXP2F(acc[2] + mbv[2] + t2);
                float p3 = EXP2F(acc[3] + mbv[3] + t3);
                ls += (p0 + p1) + (p2 + p3);
                d00 = pk2bf(p0, p1); d01 = pk2bf(p2, p3);
            }
            {
                const int kt = 2 * c + 1;
                short8 af = *(const short8*)((const char*)Kl + (kt * 16 + m) * 80 + 16 * g);
                f32x4 acc = __builtin_amdgcn_mfma_f32_16x16x32_bf16(af, qf, zero, 0, 0, 0);
                f32x4 mbv = *(const f32x4*)(mb + kt * 16 + 4 * g);
                int2 td = *(const int2*)(triQ + kt * 256);
                float t0 = __uint_as_float((unsigned)td.x << 16);
                float t1 = __uint_as_float((unsigned)td.x & 0xffff0000u);
                float t2 = __uint_as_float((unsigned)td.y << 16);
                float t3 = __uint_as_float((unsigned)td.y & 0xffff0000u);
                float p0 = EXP2F(acc[0] + mbv[0] + t0);
                float p1 = EXP2F(acc[1] + mbv[1] + t1);
                float p2 = EXP2F(acc[2] + mbv[2] + t2);
                float p3 = EXP2F(acc[3] + mbv[3] + t3);
                ls += (p0 + p1) + (p2 + p3);
                d10 = pk2bf(p0, p1); d11 = pk2bf(p2, p3);
            }
            int pk0 = odd ? d10 : d00;
            int pk1 = odd ? d11 : d01;
            int pk2 = odd ? d00 : d10;
            int pk3 = odd ? d01 : d11;

            int dA0 = __builtin_amdgcn_ds_bpermute(idxA, pk0);
            int dA1 = __builtin_amdgcn_ds_bpermute(idxA, pk1);
            int dB0 = __builtin_amdgcn_ds_bpermute(idxB, pk2);
            int dB1 = __builtin_amdgcn_ds_bpermute(idxB, pk3);
            int4v bi;
            bi.x = low ? dA0 : dB0;
            bi.y = low ? dA1 : dB1;
            bi.z = low ? dB0 : dA0;
            bi.w = low ? dB1 : dA1;
            short8 bs = __builtin_bit_cast(short8, bi);

            short8 av0 = *(const short8*)(VcB0 + c * 64 + 16 * g);
            short8 av1 = *(const short8*)(VcB1 + c * 64 + 16 * g);
            o0 = __builtin_amdgcn_mfma_f32_16x16x32_bf16(av0, bs, o0, 0, 0, 0);
            o1 = __builtin_amdgcn_mfma_f32_16x16x32_bf16(av1, bs, o1, 0, 0, 0);
        }
        ls += __shfl_xor(ls, 16, 64);
        ls += __shfl_xor(ls, 32, 64);
        float inv = 1.0f / ls;

        ushort4 s0, s1;
        s0.x = f2bf(o0[0] * inv * gacc[0][0]);
        s0.y = f2bf(o0[1] * inv * gacc[0][1]);
        s0.z = f2bf(o0[2] * inv * gacc[0][2]);
        s0.w = f2bf(o0[3] * inv * gacc[0][3]);
        s1.x = f2bf(o1[0] * inv * gacc[1][0]);
        s1.y = f2bf(o1[1] * inv * gacc[1][1]);
        s1.z = f2bf(o1[2] * inv * gacc[1][2]);
        s1.w = f2bf(o1[3] * inv * gacc[1][3]);
        *(ushort4*)(Qg + qrow * 40 + 4 * g) = s0;           // OG over Q (own rows)
        *(ushort4*)(Qg + qrow * 40 + 16 + 4 * g) = s1;

        // ===== write prefetched weights into the other buffer =====
        if (h < 3) {
            char* db = WBUF + ((h + 1) & 1) * 43008;
            { int sl = tid >> 9, e = tid & 511, row = e >> 4, c8 = e & 15;
              *(short8*)(db + sl * 8192 +
                         ((row * 256 + c8 * 16) ^ ((row & 7) << 4))) = sv0; }
            { int gi = 1024 + tid; int sl = gi >> 9, e = gi & 511, row = e >> 4, c8 = e & 15;
              *(short8*)(db + sl * 8192 +
                         ((row * 256 + c8 * 16) ^ ((row & 7) << 4))) = sv1; }
            if (tid < 512) { int n = tid >> 2, k8 = tid & 3;
              *(short8*)(db + 32768 + n * 80 + k8 * 16) = sv2; }
        }

        // ===== partial output projection (wave-local rows, no barrier) =====
        {
            short8 a = *(const short8*)((const char*)Qg + qrow * 80 + 16 * g);
            #pragma unroll
            for (int nt = 0; nt < 8; ++nt) {
                short8 b = *(const short8*)(wb + 32768 + (nt * 16 + m) * 80 + 16 * g);
                oacc[nt] = __builtin_amdgcn_mfma_f32_16x16x32_bf16(b, a, oacc[nt], 0, 0, 0);
            }
        }
        __syncthreads();   // all reads done before next head's proj overwrites
    }

    // ===== epilogue: + o_b, fp32 store =====
    const int orow = i * 256 + qrow;
    #pragma unroll
    for (int nt = 0; nt < 8; ++nt) {
        int col = nt * 16 + 4 * g;
        float4 bv = *(const float4*)(o_b + col);
        float4 o;
        o.x = oacc[nt][0] + bv.x;
        o.y = oacc[nt][1] + bv.y;
        o.z = oacc[nt][2] + bv.z;
        o.w = oacc[nt][3] + bv.w;
        *(float4*)(out + (size_t)orow * 128 + col) = o;
    }
}

// ---------------------------------------------------------------------------
extern "C" void kernel_launch(void* const* d_in, const int* in_sizes, int n_in,
                              void* d_out, int out_size, void* d_ws, size_t ws_size,
                              hipStream_t stream) {
    (void)in_sizes; (void)n_in; (void)out_size; (void)ws_size;
    const float* x    = (const float*)d_in[0];
    const float* mask = (const float*)d_in[1];
    const float* ln_w = (const float*)d_in[2];
    const float* ln_b = (const float*)d_in[3];
    const float* tri_w= (const float*)d_in[4];
    const float* q_w  = (const float*)d_in[5];
    const float* k_w  = (const float*)d_in[6];
    const float* v_w  = (const float*)d_in[7];
    const float* g_w  = (const float*)d_in[8];
    const float* g_b  = (const float*)d_in[9];
    const float* o_w  = (const float*)d_in[10];
    const float* o_b  = (const float*)d_in[11];

    char* ws = (char*)d_ws;
    unsigned short* xn  = (unsigned short*)(ws);                 // 16 MB
    unsigned short* tri = (unsigned short*)(ws + 16777216);      // 512 KB tiled
    unsigned short* wt  = (unsigned short*)(ws + 17301504);      // 160 KB

    ln_prep_kernel<<<8512, 256, 0, stream>>>(x, ln_w, ln_b, tri_w,
                                             q_w, k_w, v_w, g_w, o_w,
                                             xn, tri, wt);
    mega_kernel<<<256, 1024, 0, stream>>>(xn, wt, g_b, mask, tri, o_b,
                                          (float*)d_out);
}